// Round 17
// baseline (54.125 us; speedup 1.0000x reference)
//
#include <hip/hip_runtime.h>
#include <hip/hip_bf16.h>
#include <math.h>

#define T_LEN   7680
#define NSEG    59
#define NBINS   45
#define NTHR    256    // 4 waves; each wave owns one channel
#define NBLK    1024   // 1024 x 4 = 4096 channels; LDS 48KB -> 3 blocks/CU

using bf16x8 = __attribute__((ext_vector_type(8))) short;
using f32x4  = __attribute__((ext_vector_type(4))) float;
using f32x16 = __attribute__((ext_vector_type(16))) float;

__device__ __forceinline__ unsigned f2bf(float f) {
    unsigned u = __builtin_bit_cast(unsigned, f);
    return (u + 0x7FFFu + ((u >> 16) & 1u)) >> 16;   // RNE fp32->bf16
}

// mt_lds staging swizzle (R12-R15 proven): rows stride 512 B; on the read
// side offsets within a row are <512 so (a>>9)&7 == row&7.
__device__ __forceinline__ unsigned physB(unsigned a) {
    return a ^ (((a >> 9) & 7u) << 4);
}

// Basis table mt[96][256] bf16 (detrend+window folded; R2-proven math):
//   col j=2i: w_n*cos(2pi(i+1)n/256); col j=2i+1: -w_n*sin(...);
//   col 0 adds +0.25 (exact detrend correction for k=1 real part).
//   Rows 90..95 zero (dummy cols of ct32=2; their bins are masked).
__global__ void build_basis_kernel(unsigned short* __restrict__ mt) {
    int j = blockIdx.x, n = threadIdx.x;
    const float TH = 0.02454369260617026f;           // 2*pi/256
    float w = 0.5f - 0.5f * cosf((float)n * TH);     // periodic hann
    float v = 0.f;
    if (j < 90) {
        int k = (j >> 1) + 1;
        int m = (k * n) & 255;                       // exact periodic reduction
        float th = (float)m * TH;
        v = (j & 1) ? (-w * sinf(th)) : (w * cosf(th));
        if (j == 0) v += 0.25f;                      // fold detrend into k=1 re
    }
    mt[j * 256 + n] = (unsigned short)f2bf(v);
}

// 32x32x16 MFMA wave-private design: B-reads halve to 96/channel (the 4x
// rt-redundancy of the 16x16 design was the shared ~46us wall of R12/R15).
// Registers: acc 3x16=48, natural demand ~81 -> needs lb(256,3), the ONLY
// config the allocator ever granted >100 regs under (R2/R5: 144). 12
// waves/CU = exactly 3/EU = LDS-limited occupancy -> no squeeze motive.
// Ledger: no MFMA guards (R3-R5), no breg hoist/launder/DMA (R7-R11,R14:
// squeeze/spill triggers), XOR applied LAST in B addressing (R13 carry bug),
// junk rows via clamp + fold mask (R15-proven).
__global__ __launch_bounds__(NTHR, 3)
void welch_main_kernel(const float* __restrict__ x,
                       const unsigned short* __restrict__ mt,
                       float* __restrict__ out) {
    __shared__ __align__(16) unsigned short mt_lds[96 * 256];  // 49152 B

    const int tid  = threadIdx.x;
    const int lane = tid & 63;
    const int w    = tid >> 6;

    // ---- stage mt (3072 x 16B = 12 * 256), physB-swizzled
    {
        const uint4* mt4 = reinterpret_cast<const uint4*>(mt);
        #pragma unroll
        for (int i = 0; i < 12; ++i) {
            int c = i * NTHR + tid;
            uint4 v = mt4[c];
            *reinterpret_cast<uint4*>((char*)mt_lds + physB((unsigned)c * 16u)) = v;
        }
    }
    __syncthreads();   // the only barrier in the kernel

    const int ch = blockIdx.x * 4 + w;
    const float* gx = x + (size_t)ch * T_LEN;
    const int c32 = lane & 31;          // A row within tile / B col within tile
    const int hi  = lane >> 5;          // k-chunk selector

    // B: col j = ct32*32 + c32; byte = j*512 + ks*32 + hi*16 (disjoint bit
    // ranges), XOR swz=(j&7)<<4 = (c32&7)<<4 applied LAST.
    const unsigned bcol  = (unsigned)(((lane & 31)) * 512 + hi * 16);
    const unsigned swz   = (unsigned)((c32 & 7) << 4);

    float p[3] = {0.f, 0.f, 0.f};

    #pragma unroll
    for (int rt2 = 0; rt2 < 2; ++rt2) {
        const int row     = rt2 * 32 + c32;
        const int row_eff = row > 58 ? 58 : row;        // clamp junk rows
        const float* rowp = gx + row_eff * 128 + hi * 8;

        f32x16 acc0 = (f32x16)(0.f);
        f32x16 acc1 = (f32x16)(0.f);
        f32x16 acc2 = (f32x16)(0.f);

        #pragma unroll 1
        for (int ks = 0; ks < 16; ++ks) {
            // A-frag: 8 contiguous samples at row(row_eff), k=ks*16+hi*8
            f32x4 x0 = *reinterpret_cast<const f32x4*>(rowp + ks * 16);
            f32x4 x1 = *reinterpret_cast<const f32x4*>(rowp + ks * 16 + 4);
            unsigned d0 = f2bf(x0[0]) | (f2bf(x0[1]) << 16);
            unsigned d1 = f2bf(x0[2]) | (f2bf(x0[3]) << 16);
            unsigned d2 = f2bf(x1[0]) | (f2bf(x1[1]) << 16);
            unsigned d3 = f2bf(x1[2]) | (f2bf(x1[3]) << 16);
            uint4 pk = {d0, d1, d2, d3};
            bf16x8 a = __builtin_bit_cast(bf16x8, pk);
            const unsigned koff = bcol + (unsigned)(ks * 32);
            {
                bf16x8 b = *reinterpret_cast<const bf16x8*>(
                    (char*)mt_lds + ((koff + 0u * 16384u) ^ swz));
                acc0 = __builtin_amdgcn_mfma_f32_32x32x16_bf16(a, b, acc0, 0, 0, 0);
            }
            {
                bf16x8 b = *reinterpret_cast<const bf16x8*>(
                    (char*)mt_lds + ((koff + 1u * 16384u) ^ swz));
                acc1 = __builtin_amdgcn_mfma_f32_32x32x16_bf16(a, b, acc1, 0, 0, 0);
            }
            {
                bf16x8 b = *reinterpret_cast<const bf16x8*>(
                    (char*)mt_lds + ((koff + 2u * 16384u) ^ swz));
                acc2 = __builtin_amdgcn_mfma_f32_32x32x16_bf16(a, b, acc2, 0, 0, 0);
            }
        }

        // square-sum fold. C/D: col=lane&31, row_in = (r&3)+8*(r>>2)+4*hi.
        // rt2=1 junk mask (global row = 32+row_in < 59 -> row_in < 27):
        // regs 0-11 always; 12-14 iff hi==0; 15 never.
        #pragma unroll
        for (int r = 0; r < 16; ++r) {
            bool keep = (rt2 == 0) || (r < 12) || (r < 15 && hi == 0);
            if (keep) {
                p[0] += acc0[r] * acc0[r];
                p[1] += acc1[r] * acc1[r];
                p[2] += acc2[r] * acc2[r];
            }
        }
    }

    // ---- wave-local reduction + output
    const float CNORM = 2.0f / (24576.0f * 59.0f);     // fs*sum(w^2) = 256*96
    #pragma unroll
    for (int ct = 0; ct < 3; ++ct) {
        float v = p[ct];
        v += __shfl_xor(v, 32);    // sum the two hi-halves (row groups)
        v += __shfl_xor(v, 1);     // re^2 + im^2 (adjacent cols)
        int bin = ct * 16 + (c32 >> 1);
        if (hi == 0 && (lane & 1) == 0 && bin < NBINS)
            out[(size_t)ch * NBINS + bin] = log1pf(v * CNORM);
    }
}

extern "C" void kernel_launch(void* const* d_in, const int* in_sizes, int n_in,
                              void* d_out, int out_size, void* d_ws, size_t ws_size,
                              hipStream_t stream) {
    const float* x = (const float*)d_in[0];
    float* out = (float*)d_out;
    unsigned short* mt = (unsigned short*)d_ws;   // 96*256*2 = 49152 B

    build_basis_kernel<<<96, 256, 0, stream>>>(mt);
    welch_main_kernel<<<NBLK, NTHR, 0, stream>>>(x, mt, out);
}

// Round 18
// 51.780 us; speedup vs baseline: 1.0453x; 1.0453x over previous
//
#include <hip/hip_runtime.h>
#include <hip/hip_bf16.h>
#include <math.h>

#define T_LEN   7680
#define NSEG    59
#define NBINS   45
#define CH_PB   16     // channels per block
#define NBLK    256    // 1 block per CU, zero tail
#define NTHR    512    // 8 waves

using bf16x8 = __attribute__((ext_vector_type(8))) short;
using f32x4  = __attribute__((ext_vector_type(4))) float;

__device__ __forceinline__ unsigned f2bf(float f) {
    unsigned u = __builtin_bit_cast(unsigned, f);
    return (u + 0x7FFFu + ((u >> 16) & 1u)) >> 16;   // RNE fp32->bf16
}

// xs swizzle (R9-R15 proven): rows stride 256 B -> mix bits 8-10 into 4-6.
__device__ __forceinline__ unsigned phys(unsigned a) {
    return a ^ (((a >> 8) & 7u) << 4);
}
// mt_lds swizzle (R12-R17 proven): rows stride 512 B -> bits 9-11 into 4-6.
__device__ __forceinline__ unsigned physB(unsigned a) {
    return a ^ (((a >> 9) & 7u) << 4);
}

// Basis table mt[96][256] bf16 (detrend+window folded; R2-proven math):
//   col j=2i: w_n*cos(2pi(i+1)n/256); col j=2i+1: -w_n*sin(...);
//   col 0 adds +0.25 (exact detrend correction for k=1 real part).
//   Rows 90..95 zero (dummy cols; their bins masked at output).
__global__ void build_basis_kernel(unsigned short* __restrict__ mt) {
    int j = blockIdx.x, n = threadIdx.x;
    const float TH = 0.02454369260617026f;           // 2*pi/256
    float w = 0.5f - 0.5f * cosf((float)n * TH);     // periodic hann
    float v = 0.f;
    if (j < 90) {
        int k = (j >> 1) + 1;
        int m = (k * n) & 255;                       // exact periodic reduction
        float th = (float)m * TH;
        v = (j & 1) ? (-w * sinf(th)) : (w * cosf(th));
        if (j == 0) v += 0.25f;                      // fold detrend into k=1 re
    }
    mt[j * 256 + n] = (unsigned short)f2bf(v);
}

// DMA-pipelined fortress. Little's law: hiding HBM latency needs ~9.4KB in
// flight per CU; register loads give 0.5KB (the R12-R17 ~46-54us plateau);
// global_load_lds gives 30KB/channel at ZERO register cost (allocator-proof:
// natural live set ~60 regs, under even the worst 64-reg squeeze target).
// Raw s_barrier + manual lgkmcnt (NOT __syncthreads, which drains vmcnt and
// would serialize the DMA). Per-wave vmcnt(0) is a complete xf-readiness
// guarantee: conv reads exactly the chunks its own wave DMA'd.
// Ledger: no MFMA guards (R3-R5), no breg hoist/launder (R7-R11), XOR last
// (R13), natural regs <= 64 (R14/R15), full-col ownership -> no psum.
__global__ __launch_bounds__(NTHR, 2)
void welch_main_kernel(const float* __restrict__ x,
                       const unsigned short* __restrict__ mt,
                       float* __restrict__ out) {
    __shared__ __align__(16) unsigned short mt_lds[96 * 256];  // 49152 B
    __shared__ __align__(16) float          xf[2][T_LEN];      // 61440 B
    __shared__ __align__(16) unsigned short xs[8320];          // 16640 B

    const int tid  = threadIdx.x;
    const int lane = tid & 63;
    const int w    = tid >> 6;
    const int ch0  = blockIdx.x * CH_PB;
    const float* gx = x + (size_t)ch0 * T_LEN;

    // DMA one channel (1920 x 16B) into xf[buf]; wave-uniform LDS base,
    // per-lane global source; zero VGPR cost. Guard c<1920 is wave-uniform.
    auto issue_x = [&](int buf, int cc) {
        const float* gxc = gx + (size_t)cc * T_LEN;
        #pragma unroll
        for (int i = 0; i < 4; ++i) {
            int c = i * NTHR + tid;
            if (c < 1920) {
                char* lp = (char*)&xf[buf][0] + (size_t)(i * NTHR + (tid & ~63)) * 16;
                __builtin_amdgcn_global_load_lds(
                    (const __attribute__((address_space(1))) void*)(gxc + (size_t)c * 4),
                    (__attribute__((address_space(3))) void*)lp, 16, 0, 0);
            }
        }
    };

    // ---- prologue: DMA ch0; stage mt (3072 x 16B, physB); zero xs pad
    issue_x(0, 0);
    {
        const uint4* mt4 = reinterpret_cast<const uint4*>(mt);
        #pragma unroll
        for (int i = 0; i < 6; ++i) {
            int c = i * NTHR + tid;
            uint4 v = mt4[c];
            *reinterpret_cast<uint4*>((char*)mt_lds + physB((unsigned)c * 16u)) = v;
        }
    }
    if (tid < 160) {
        unsigned a = phys(15360u + (unsigned)tid * 8u);
        *reinterpret_cast<uint2*>((char*)xs + a) = make_uint2(0u, 0u);
    }
    asm volatile("s_waitcnt vmcnt(0) lgkmcnt(0)" ::: "memory");
    __builtin_amdgcn_s_barrier();
    __builtin_amdgcn_sched_barrier(0);

    const int col0 = lane & 15;
    const int q    = lane >> 4;

    #pragma unroll 1
    for (int cc = 0; cc < CH_PB; ++cc) {
        const int par = cc & 1;

        // ---- own-wave DMA drain (xf[par] chunks == the ones we read below)
        if (cc) {
            asm volatile("s_waitcnt vmcnt(0)" ::: "memory");
            __builtin_amdgcn_sched_barrier(0);
        }
        // ---- issue next channel NOW: in-flight window = this whole channel
        if (cc + 1 < CH_PB) issue_x(par ^ 1, cc + 1);

        // ---- convert: xf[par] (LDS fp32) -> xs (bf16, phys-swizzled)
        #pragma unroll
        for (int i = 0; i < 4; ++i) {
            int c = i * NTHR + tid;
            if (c < 1920) {
                f32x4 xv = *reinterpret_cast<const f32x4*>(&xf[par][4 * c]);
                unsigned b0 = f2bf(xv[0]), b1 = f2bf(xv[1]);
                unsigned b2 = f2bf(xv[2]), b3 = f2bf(xv[3]);
                uint2 pk; pk.x = b0 | (b1 << 16); pk.y = b2 | (b3 << 16);
                *reinterpret_cast<uint2*>((char*)xs + phys((unsigned)c * 8u)) = pk;
            }
        }
        asm volatile("s_waitcnt lgkmcnt(0)" ::: "memory");  // xs writes landed
        __builtin_amdgcn_s_barrier();
        __builtin_amdgcn_sched_barrier(0);

        // ---- G+E+out: wave w<6 owns col-tile ct=w fully (no cross-wave sum)
        if (w < 6) {
            const int j    = w * 16 + col0;            // B col
            const unsigned bb   = (unsigned)(j * 512 + q * 16);
            const unsigned bswz = (unsigned)((col0 & 7) << 4);
            bf16x8 b[8];
            #pragma unroll
            for (int k0 = 0; k0 < 8; ++k0)
                b[k0] = *reinterpret_cast<const bf16x8*>(
                    (char*)mt_lds + ((bb + (unsigned)(k0 * 64)) ^ bswz));

            float p = 0.f;
            #pragma unroll
            for (int rt = 0; rt < 4; ++rt) {
                const int row     = rt * 16 + col0;
                const int row_eff = row > 58 ? 58 : row;    // clamp junk rows
                const unsigned abase = (unsigned)(row_eff * 256);
                f32x4 acc = (f32x4){0.f, 0.f, 0.f, 0.f};
                #pragma unroll
                for (int k0 = 0; k0 < 8; ++k0) {
                    bf16x8 a = *reinterpret_cast<const bf16x8*>(
                        (char*)xs + phys(abase + (unsigned)(k0 * 64 + q * 16)));
                    acc = __builtin_amdgcn_mfma_f32_16x16x32_bf16(a, b[k0], acc, 0, 0, 0);
                }
                // C/D: col=lane&15, row = rt*16 + q*4 + r; mask rows >= 59
                const int rowbase = rt * 16 + q * 4;
                #pragma unroll
                for (int r = 0; r < 4; ++r)
                    if (rowbase + r < NSEG) p += acc[r] * acc[r];
            }
            // col totals: sum q-groups, then re^2+im^2 across col pair
            p += __shfl_xor(p, 16);
            p += __shfl_xor(p, 32);
            p += __shfl_xor(p, 1);
            const int bin = (j >> 1);                  // = w*8 + col0/2
            if (q == 0 && (col0 & 1) == 0 && bin < NBINS) {
                const float CNORM = 2.0f / (24576.0f * 59.0f); // fs*sum(w^2)*nseg
                out[(size_t)(ch0 + cc) * NBINS + bin] = log1pf(p * CNORM);
            }
        }
        asm volatile("s_waitcnt lgkmcnt(0)" ::: "memory");  // xs reads done
        __builtin_amdgcn_s_barrier();
        __builtin_amdgcn_sched_barrier(0);
    }
}

extern "C" void kernel_launch(void* const* d_in, const int* in_sizes, int n_in,
                              void* d_out, int out_size, void* d_ws, size_t ws_size,
                              hipStream_t stream) {
    const float* x = (const float*)d_in[0];
    float* out = (float*)d_out;
    unsigned short* mt = (unsigned short*)d_ws;   // 96*256*2 = 49152 B

    build_basis_kernel<<<96, 256, 0, stream>>>(mt);
    welch_main_kernel<<<NBLK, NTHR, 0, stream>>>(x, mt, out);
}